// Round 10
// baseline (765.059 us; speedup 1.0000x reference)
//
#include <hip/hip_runtime.h>

#define FBANK_MEAN 15.41663f
#define FBANK_STD  6.55582f

constexpr int Bb   = 32;
constexpr int T    = 3200;
constexpr int D    = 128;
constexpr int C    = 512;    // embed_dim
constexpr int QD   = 256;    // quant_dim
constexpr int QN   = 1024;   // quant_n
constexpr int Tp   = 200;
constexpr int Fp   = 8;
constexpr int NTOK = Tp * Fp;     // 1600 tokens per batch
constexpr int TOKS = Bb * NTOK;   // 51200
constexpr int TPB  = 16;          // tokens per block

typedef float v4fe __attribute__((ext_vector_type(4)));

#define V4(p) (*(const v4fe*)(p))

// ---------------------------------------------------------------------------
// Merged prep (identical to round-9 verified version):
// [0,512): transpose conv_w (512x256)->wt(256x512).
// [512,1536): l2-normalize codebook row, store d-major cbt[d*1024+k].
// 1536: proj colsums sv[256] + embed_len.
__global__ void prep_all(const float* __restrict__ w, const float* __restrict__ proj,
                         const float* __restrict__ cb, const int* __restrict__ ilens,
                         float* __restrict__ wt, float* __restrict__ cbt,
                         float* __restrict__ sv, int* __restrict__ out_len) {
    const int bid = blockIdx.x, tid = threadIdx.x;
    if (bid < 512) {
        int idx = bid * 256 + tid;          // idx = k*512 + c
        int k = idx >> 9, c = idx & 511;
        wt[idx] = w[c * 256 + k];
    } else if (bid < 1536) {
        __shared__ float part[4];
        int k = bid - 512;                  // code row
        float v = cb[k * QD + tid];
        float s = v * v;
        #pragma unroll
        for (int off = 32; off >= 1; off >>= 1) s += __shfl_xor(s, off);
        if ((tid & 63) == 0) part[tid >> 6] = s;
        __syncthreads();
        float tot = part[0] + part[1] + part[2] + part[3];
        cbt[tid * QN + k] = v * rsqrtf(tot + 1e-12f);
    } else {
        float acc = 0.f;
        for (int k = 0; k < C; ++k) acc += proj[k * QD + tid];
        sv[tid] = acc;
        if (tid < Bb) {
            int cnt = ilens[tid] >> 4;
            if (cnt > Tp) cnt = Tp;
            if (cnt < 0) cnt = 0;
            out_len[tid] = Fp * cnt;
        }
    }
}

// ---------------------------------------------------------------------------
// Fused: patch -> conv(fp32) -> mean -> proj(fp32, -mu*colsum) ->
//        exact fp32 sims -> argmax.  Round-9 verified math; LDS rearranged:
// patch (16 KB) and xp (16 KB) now ALIAS the feats buffer (32 KB), with one
// extra "all-reads-done" barrier per GEMM phase. LDS 49 -> ~33 KB, so
// occupancy rises from 3 to 4 blocks/CU, hiding barrier drains.
// LN rsqrt(var) and xp l2norm are per-token positive scalings -> dropped.
__global__ __launch_bounds__(256, 4) void fused_tok(
    const float* __restrict__ xs,    // B*T*D
    const float* __restrict__ wt,    // 256 x 512 (k-major)
    const float* __restrict__ proj,  // 512 x 256 (k-major)
    const float* __restrict__ cbt,   // 256 x 1024 (d-major, rows l2-normed)
    const float* __restrict__ sv,    // 256 colsum(proj)
    int* __restrict__ out_ind)       // TOKS
{
    // Single 32 KB buffer. Aliases:
    //   patch = smem[0:4096)   (16 tok x 256, conv input)
    //   feats = smem[0:8192)   (16 tok x 512, conv output / proj input)
    //   xp    = smem[0:4096)   (16 tok x 256, proj output / sims input)
    __shared__ __align__(16) float smem[TPB * 512];
    __shared__ float mu_s[TPB];
    __shared__ float rvs[4][TPB];
    __shared__ int   rif[4][TPB];

    float* const patch = smem;
    float* const feats = smem;
    float* const xp    = smem;

    const int tid  = threadIdx.x;
    const int lane = tid & 63;
    const int wv   = tid >> 6;               // wave id 0..3
    const int g0   = blockIdx.x * TPB;
    const int b    = g0 / NTOK;
    const int n0   = g0 - b * NTOK;
    const int tp0  = n0 >> 3;                // first of the two tp rows

    const v4fe zero4 = {0.f, 0.f, 0.f, 0.f};

    // ---- 1. patch staging: 32 time-rows x 128 cols -> patch[t][k] --------
    {
        const v4fe* src = (const v4fe*)(xs + ((size_t)b * T + (size_t)tp0 * 16) * D);
        const float inv = 1.0f / (2.0f * FBANK_STD);
        #pragma unroll
        for (int r = 0; r < 4; ++r) {
            int f4 = r * 256 + tid;          // float4 index 0..1023
            v4fe v = (src[f4] - FBANK_MEAN) * inv;
            int i = f4 >> 5;                 // time row 0..31
            int d = (f4 & 31) << 2;          // fbank col
            int t = ((i >> 4) << 3) + (d >> 4);
            int k = ((i & 15) << 4) + (d & 15);
            *(v4fe*)&patch[t * 256 + k] = v;
        }
    }
    __syncthreads();

    // ---- 2. conv: Mr=16 tok x Nr=4 ch; waves = (ch-half, K-half) ---------
    {
        const int c = wv & 1;                // channel half
        const int h = wv >> 1;               // K half
        v4fe acc[16];
        #pragma unroll
        for (int j = 0; j < 16; ++j) acc[j] = zero4;
        const float* wb = wt + c * 256 + 4 * lane;
        for (int k4 = 0; k4 < 32; ++k4) {
            const int kb = h * 128 + k4 * 4;
            v4fe w0 = V4(wb + (kb + 0) * 512);
            v4fe w1 = V4(wb + (kb + 1) * 512);
            v4fe w2 = V4(wb + (kb + 2) * 512);
            v4fe w3 = V4(wb + (kb + 3) * 512);
            #pragma unroll
            for (int hh = 0; hh < 2; ++hh) {
                v4fe xv[8];
                #pragma unroll
                for (int j = 0; j < 8; ++j)    // wave-uniform broadcasts
                    xv[j] = V4(patch + (hh * 8 + j) * 256 + kb);
                #pragma unroll
                for (int j = 0; j < 8; ++j) {
                    acc[hh * 8 + j] += xv[j].x * w0;
                    acc[hh * 8 + j] += xv[j].y * w1;
                    acc[hh * 8 + j] += xv[j].z * w2;
                    acc[hh * 8 + j] += xv[j].w * w3;
                }
            }
        }
        __syncthreads();                     // all patch reads done (aliasing)
        float* fb0 = &feats[c * 256 + 4 * lane];
        if (h == 0) {
            #pragma unroll
            for (int j = 0; j < 16; ++j)
                *(v4fe*)(fb0 + j * 512) = acc[j];
        }
        __syncthreads();
        if (h == 1) {
            #pragma unroll
            for (int j = 0; j < 16; ++j) {
                v4fe o = V4(fb0 + j * 512);
                o += acc[j];
                *(v4fe*)(fb0 + j * 512) = o;
            }
        }
    }
    __syncthreads();

    // ---- 3. per-token mean of feats (var scaling is argmax-invariant) ----
    {
        const int t = tid >> 4, l = tid & 15;
        float s1 = 0.f;
        #pragma unroll
        for (int m = 0; m < 32; ++m) s1 += feats[t * 512 + l + 16 * m];
        #pragma unroll
        for (int off = 8; off >= 1; off >>= 1) s1 += __shfl_xor(s1, off);
        if (l == 0) mu_s[t] = s1 * (1.0f / 512.0f);
    }
    __syncthreads();

    // ---- 4. proj: Mr=8 tok x Nr=4 qd; waves = (tok-half, K-half) ---------
    {
        const int g = wv & 1;                // token half
        const int h = wv >> 1;               // K half (256 each)
        v4fe acc[8];
        #pragma unroll
        for (int j = 0; j < 8; ++j) acc[j] = zero4;
        const float* pb = proj + 4 * lane;
        const float* fb0 = &feats[(g * 8) * 512];
        for (int k4 = 0; k4 < 64; ++k4) {
            const int kb = h * 256 + k4 * 4;
            v4fe w0 = V4(pb + (kb + 0) * 256);
            v4fe w1 = V4(pb + (kb + 1) * 256);
            v4fe w2 = V4(pb + (kb + 2) * 256);
            v4fe w3 = V4(pb + (kb + 3) * 256);
            v4fe xv[8];
            #pragma unroll
            for (int j = 0; j < 8; ++j)        // broadcasts
                xv[j] = V4(fb0 + j * 512 + kb);
            #pragma unroll
            for (int j = 0; j < 8; ++j) {
                acc[j] += xv[j].x * w0;
                acc[j] += xv[j].y * w1;
                acc[j] += xv[j].z * w2;
                acc[j] += xv[j].w * w3;
            }
        }
        __syncthreads();                     // all feats reads done (aliasing)
        float* xb = &xp[(g * 8) * 256 + 4 * lane];
        if (h == 0) {                        // epilogue: y - mu * colsum(proj)
            v4fe s4 = V4(sv + 4 * lane);
            #pragma unroll
            for (int j = 0; j < 8; ++j) {
                v4fe o = acc[j] - mu_s[g * 8 + j] * s4;
                *(v4fe*)(xb + j * 256) = o;
            }
        }
        __syncthreads();
        if (h == 1) {
            #pragma unroll
            for (int j = 0; j < 8; ++j) {
                v4fe o = V4(xb + j * 256);
                o += acc[j];
                *(v4fe*)(xb + j * 256) = o;
            }
        }
    }
    __syncthreads();

    // ---- 5. sims: Mr=16 tok x Nr=4 codes; waves = code-quarters ----------
    {
        const int cq = wv;                   // code quarter
        v4fe acc[16];
        #pragma unroll
        for (int j = 0; j < 16; ++j) acc[j] = zero4;
        const float* cbase = cbt + cq * 256 + 4 * lane;
        for (int d4 = 0; d4 < 64; ++d4) {
            const int db = d4 * 4;
            v4fe w0 = V4(cbase + (db + 0) * 1024);
            v4fe w1 = V4(cbase + (db + 1) * 1024);
            v4fe w2 = V4(cbase + (db + 2) * 1024);
            v4fe w3 = V4(cbase + (db + 3) * 1024);
            #pragma unroll
            for (int hh = 0; hh < 2; ++hh) {
                v4fe xv[8];
                #pragma unroll
                for (int j = 0; j < 8; ++j)    // broadcasts
                    xv[j] = V4(xp + (hh * 8 + j) * 256 + db);
                #pragma unroll
                for (int j = 0; j < 8; ++j) {
                    acc[hh * 8 + j] += xv[j].x * w0;
                    acc[hh * 8 + j] += xv[j].y * w1;
                    acc[hh * 8 + j] += xv[j].z * w2;
                    acc[hh * 8 + j] += xv[j].w * w3;
                }
            }
        }
        // argmax: per-thread over 4 codes (ascending ids), 64-lane butterfly
        const int base = cq * 256 + 4 * lane;
        #pragma unroll
        for (int j = 0; j < 16; ++j) {
            float bv = acc[j].x; int bi = base;
            if (acc[j].y > bv) { bv = acc[j].y; bi = base + 1; }
            if (acc[j].z > bv) { bv = acc[j].z; bi = base + 2; }
            if (acc[j].w > bv) { bv = acc[j].w; bi = base + 3; }
            #pragma unroll
            for (int off = 32; off >= 1; off >>= 1) {
                float ov = __shfl_xor(bv, off);
                int   oi = __shfl_xor(bi, off);
                if (ov > bv || (ov == bv && oi < bi)) { bv = ov; bi = oi; }
            }
            if (lane == 0) { rvs[cq][j] = bv; rif[cq][j] = bi; }
        }
    }
    __syncthreads();
    if (tid < TPB) {
        float bv = rvs[0][tid];
        int   bi = rif[0][tid];
        #pragma unroll
        for (int w = 1; w < 4; ++w) {        // quarters ascending: strict >
            float ov = rvs[w][tid];
            if (ov > bv) { bv = ov; bi = rif[w][tid]; }
        }
        out_ind[g0 + tid] = bi;
    }
}

// ---------------------------------------------------------------------------
extern "C" void kernel_launch(void* const* d_in, const int* in_sizes, int n_in,
                              void* d_out, int out_size, void* d_ws, size_t ws_size,
                              hipStream_t stream) {
    const float* xs       = (const float*)d_in[0];   // (32,3200,128) f32
    const int*   ilens    = (const int*)  d_in[1];   // (32,) i32
    const float* conv_w   = (const float*)d_in[2];   // (512,1,16,16) f32
    const float* proj     = (const float*)d_in[3];   // (512,256) f32
    const float* codebook = (const float*)d_in[4];   // (1024,256) f32
    int* out = (int*)d_out;                          // 51200 ind + 32 len

    // Workspace footprint identical to passing rounds 2-4/9: 1.501 MB.
    float* wt  = (float*)d_ws;            // 256x512 = 512 KB
    float* cbt = wt + 256 * C;            // 256x1024 = 1 MB
    float* sv  = cbt + QD * QN;           // 256 floats = 1 KB

    prep_all<<<1537, 256, 0, stream>>>(conv_w, proj, codebook, ilens,
                                       wt, cbt, sv, out + TOKS);
    fused_tok<<<TOKS / TPB, 256, 0, stream>>>(xs, wt, proj, cbt, sv, out);
}

// Round 11
// 572.159 us; speedup vs baseline: 1.3371x; 1.3371x over previous
//
#include <hip/hip_runtime.h>

#define FBANK_MEAN 15.41663f
#define FBANK_STD  6.55582f

constexpr int Bb   = 32;
constexpr int T    = 3200;
constexpr int D    = 128;
constexpr int C    = 512;    // embed_dim
constexpr int QD   = 256;    // quant_dim
constexpr int QN   = 1024;   // quant_n
constexpr int Tp   = 200;
constexpr int Fp   = 8;
constexpr int NTOK = Tp * Fp;     // 1600 tokens per batch
constexpr int TOKS = Bb * NTOK;   // 51200
constexpr int TPB  = 16;          // tokens per block

typedef float v4fe __attribute__((ext_vector_type(4)));

#define V4(p) (*(const v4fe*)(p))

// ---------------------------------------------------------------------------
// Merged prep:
// [0,1024): l2-normalize codebook row k, store d-major cbt[d*1024+k].
// [1024,1280): fused conv∘LN∘proj matrix
//     M'[k][q] = sum_c W[c][k]*proj[c][q] - (mean_c W[c][k])*(sum_c proj[c][q])
//   (LN mean-subtraction folded; LN var-scale & xp l2norm are per-token
//    positive scalings -> argmax-invariant -> dropped. Verified R4/R9.)
// 1280: embed_len.
__global__ void prep_all(const float* __restrict__ w, const float* __restrict__ proj,
                         const float* __restrict__ cb, const int* __restrict__ ilens,
                         float* __restrict__ Mp, float* __restrict__ cbt,
                         int* __restrict__ out_len) {
    const int bid = blockIdx.x, tid = threadIdx.x;
    if (bid < 1024) {
        __shared__ float part[4];
        int k = bid;                        // code row
        float v = cb[k * QD + tid];
        float s = v * v;
        #pragma unroll
        for (int off = 32; off >= 1; off >>= 1) s += __shfl_xor(s, off);
        if ((tid & 63) == 0) part[tid >> 6] = s;
        __syncthreads();
        float tot = part[0] + part[1] + part[2] + part[3];
        cbt[tid * QN + k] = v * rsqrtf(tot + 1e-12f);
    } else if (bid < 1280) {
        int k = bid - 1024;                 // patch-element row of M'
        int q = tid;
        float dot = 0.f, wsum = 0.f, psum = 0.f;
        for (int c = 0; c < C; ++c) {
            float wv = w[c * 256 + k];      // wave-uniform broadcast
            float pv = proj[c * QD + q];    // coalesced
            dot  += wv * pv;
            wsum += wv;
            psum += pv;
        }
        Mp[k * 256 + q] = dot - (wsum * (1.0f / 512.0f)) * psum;
    } else {
        if (tid < Bb) {
            int cnt = ilens[tid] >> 4;
            if (cnt > Tp) cnt = Tp;
            if (cnt < 0) cnt = 0;
            out_len[tid] = Fp * cnt;
        }
    }
}

// ---------------------------------------------------------------------------
// Fused: patch -> xp = patch x M' (K=256) -> exact fp32 sims -> argmax.
// The former conv (13.4 GF) + mean + proj (13.4 GF) phases are replaced by
// one 6.7 GF GEMM via the precomputed M' -- 37% total FLOP reduction.
// GEMM tiles are the verified round-9 shapes; LDS 33 KB -> 4 blocks/CU.
__global__ __launch_bounds__(256, 3) void fused_tok(
    const float* __restrict__ xs,    // B*T*D
    const float* __restrict__ Mp,    // 256 x 256 (k-major) fused matrix
    const float* __restrict__ cbt,   // 256 x 1024 (d-major, rows l2-normed)
    int* __restrict__ out_ind)       // TOKS
{
    __shared__ __align__(16) float patch[TPB * 256];   // 16 KB
    __shared__ __align__(16) float xp[TPB * 256];      // 16 KB
    __shared__ float rvs[4][TPB];
    __shared__ int   rif[4][TPB];

    const int tid  = threadIdx.x;
    const int lane = tid & 63;
    const int wv   = tid >> 6;               // wave id 0..3
    const int g0   = blockIdx.x * TPB;
    const int b    = g0 / NTOK;
    const int n0   = g0 - b * NTOK;
    const int tp0  = n0 >> 3;                // first of the two tp rows

    const v4fe zero4 = {0.f, 0.f, 0.f, 0.f};

    // ---- 1. patch staging: 32 time-rows x 128 cols -> patch[t][k] --------
    {
        const v4fe* src = (const v4fe*)(xs + ((size_t)b * T + (size_t)tp0 * 16) * D);
        const float inv = 1.0f / (2.0f * FBANK_STD);
        #pragma unroll
        for (int r = 0; r < 4; ++r) {
            int f4 = r * 256 + tid;          // float4 index 0..1023
            v4fe v = (src[f4] - FBANK_MEAN) * inv;
            int i = f4 >> 5;                 // time row 0..31
            int d = (f4 & 31) << 2;          // fbank col
            int t = ((i >> 4) << 3) + (d >> 4);
            int k = ((i & 15) << 4) + (d & 15);
            *(v4fe*)&patch[t * 256 + k] = v;
        }
    }
    __syncthreads();

    // ---- 2. xp GEMM: Mr=8 tok x Nr=4 q; waves = (tok-half, K-half) -------
    {
        const int g = wv & 1;                // token half
        const int h = wv >> 1;               // K half (128 each)
        v4fe acc[8];
        #pragma unroll
        for (int j = 0; j < 8; ++j) acc[j] = zero4;
        const float* pb = Mp + 4 * lane;
        const float* fb0 = &patch[(g * 8) * 256];
        for (int k4 = 0; k4 < 32; ++k4) {
            const int kb = h * 128 + k4 * 4;
            v4fe w0 = V4(pb + (kb + 0) * 256);
            v4fe w1 = V4(pb + (kb + 1) * 256);
            v4fe w2 = V4(pb + (kb + 2) * 256);
            v4fe w3 = V4(pb + (kb + 3) * 256);
            v4fe xv[8];
            #pragma unroll
            for (int j = 0; j < 8; ++j)        // wave-uniform broadcasts
                xv[j] = V4(fb0 + j * 256 + kb);
            #pragma unroll
            for (int j = 0; j < 8; ++j) {
                acc[j] += xv[j].x * w0;
                acc[j] += xv[j].y * w1;
                acc[j] += xv[j].z * w2;
                acc[j] += xv[j].w * w3;
            }
        }
        float* xb = &xp[(g * 8) * 256 + 4 * lane];
        if (h == 0) {
            #pragma unroll
            for (int j = 0; j < 8; ++j)
                *(v4fe*)(xb + j * 256) = acc[j];
        }
        __syncthreads();
        if (h == 1) {
            #pragma unroll
            for (int j = 0; j < 8; ++j) {
                v4fe o = V4(xb + j * 256);
                o += acc[j];
                *(v4fe*)(xb + j * 256) = o;
            }
        }
    }
    __syncthreads();

    // ---- 3. sims: Mr=16 tok x Nr=4 codes; waves = code-quarters ----------
    {
        const int cq = wv;                   // code quarter
        v4fe acc[16];
        #pragma unroll
        for (int j = 0; j < 16; ++j) acc[j] = zero4;
        const float* cbase = cbt + cq * 256 + 4 * lane;
        for (int d4 = 0; d4 < 64; ++d4) {
            const int db = d4 * 4;
            v4fe w0 = V4(cbase + (db + 0) * 1024);
            v4fe w1 = V4(cbase + (db + 1) * 1024);
            v4fe w2 = V4(cbase + (db + 2) * 1024);
            v4fe w3 = V4(cbase + (db + 3) * 1024);
            #pragma unroll
            for (int hh = 0; hh < 2; ++hh) {
                v4fe xv[8];
                #pragma unroll
                for (int j = 0; j < 8; ++j)    // broadcasts
                    xv[j] = V4(xp + (hh * 8 + j) * 256 + db);
                #pragma unroll
                for (int j = 0; j < 8; ++j) {
                    acc[hh * 8 + j] += xv[j].x * w0;
                    acc[hh * 8 + j] += xv[j].y * w1;
                    acc[hh * 8 + j] += xv[j].z * w2;
                    acc[hh * 8 + j] += xv[j].w * w3;
                }
            }
        }
        // argmax: per-thread over 4 codes (ascending ids), 64-lane butterfly
        const int base = cq * 256 + 4 * lane;
        #pragma unroll
        for (int j = 0; j < 16; ++j) {
            float bv = acc[j].x; int bi = base;
            if (acc[j].y > bv) { bv = acc[j].y; bi = base + 1; }
            if (acc[j].z > bv) { bv = acc[j].z; bi = base + 2; }
            if (acc[j].w > bv) { bv = acc[j].w; bi = base + 3; }
            #pragma unroll
            for (int off = 32; off >= 1; off >>= 1) {
                float ov = __shfl_xor(bv, off);
                int   oi = __shfl_xor(bi, off);
                if (ov > bv || (ov == bv && oi < bi)) { bv = ov; bi = oi; }
            }
            if (lane == 0) { rvs[cq][j] = bv; rif[cq][j] = bi; }
        }
    }
    __syncthreads();
    if (tid < TPB) {
        float bv = rvs[0][tid];
        int   bi = rif[0][tid];
        #pragma unroll
        for (int w = 1; w < 4; ++w) {        // quarters ascending: strict >
            float ov = rvs[w][tid];
            if (ov > bv) { bv = ov; bi = rif[w][tid]; }
        }
        out_ind[g0 + tid] = bi;
    }
}

// ---------------------------------------------------------------------------
extern "C" void kernel_launch(void* const* d_in, const int* in_sizes, int n_in,
                              void* d_out, int out_size, void* d_ws, size_t ws_size,
                              hipStream_t stream) {
    const float* xs       = (const float*)d_in[0];   // (32,3200,128) f32
    const int*   ilens    = (const int*)  d_in[1];   // (32,) i32
    const float* conv_w   = (const float*)d_in[2];   // (512,1,16,16) f32
    const float* proj     = (const float*)d_in[3];   // (512,256) f32
    const float* codebook = (const float*)d_in[4];   // (1024,256) f32
    int* out = (int*)d_out;                          // 51200 ind + 32 len

    // Workspace: 1.25 MB (inside the 1.5 MB envelope proven by R2-4/9/10).
    float* Mp  = (float*)d_ws;            // 256x256 fused matrix = 256 KB
    float* cbt = Mp + 256 * 256;          // 256x1024 = 1 MB

    prep_all<<<1281, 256, 0, stream>>>(conv_w, proj, codebook, ilens,
                                       Mp, cbt, out + TOKS);
    fused_tok<<<TOKS / TPB, 256, 0, stream>>>(xs, Mp, cbt, out);
}

// Round 12
// 478.240 us; speedup vs baseline: 1.5997x; 1.1964x over previous
//
#include <hip/hip_runtime.h>

#define FBANK_MEAN 15.41663f
#define FBANK_STD  6.55582f

constexpr int Bb   = 32;
constexpr int T    = 3200;
constexpr int D    = 128;
constexpr int C    = 512;    // embed_dim
constexpr int QD   = 256;    // quant_dim
constexpr int QN   = 1024;   // quant_n
constexpr int Tp   = 200;
constexpr int Fp   = 8;
constexpr int NTOK = Tp * Fp;     // 1600 tokens per batch
constexpr int TOKS = Bb * NTOK;   // 51200
constexpr int TPB  = 16;          // tokens per block

typedef float v4fe __attribute__((ext_vector_type(4)));

#define V4(p) (*(const v4fe*)(p))

// ===========================================================================
// NEW PATH: sims = patch x G, G = M' x cbn^T  (needs 2.25 MB workspace)
// ===========================================================================

// prep_a: [0,32): cbt transpose-normalize, 32 codes/block, coalesced both ways.
//         [32,288): M'[k][q] = sum_c W[c][k]proj[c][q] - mean_c(W[c][k])*colsum(proj)[q]
//         288: embed_len.
__global__ void prep_a(const float* __restrict__ w, const float* __restrict__ proj,
                       const float* __restrict__ cb, const int* __restrict__ ilens,
                       float* __restrict__ Mp, float* __restrict__ cbt,
                       int* __restrict__ out_len) {
    const int bid = blockIdx.x, tid = threadIdx.x;
    if (bid < 32) {
        __shared__ float tile[32 * 257];    // padded stride: conflict-free
        __shared__ float nrm[32];
        const int k0 = bid * 32;
        const int lane = tid & 63, wv = tid >> 6;
        #pragma unroll 4
        for (int r = 0; r < 32; ++r)
            tile[r * 257 + tid] = cb[(size_t)(k0 + r) * QD + tid];
        __syncthreads();
        for (int c = 0; c < 8; ++c) {       // wave wv -> codes wv*8..+7
            int r = wv * 8 + c;
            float s = 0.f;
            #pragma unroll
            for (int m = 0; m < 4; ++m) {
                float v = tile[r * 257 + lane + 64 * m];
                s += v * v;
            }
            #pragma unroll
            for (int off = 32; off >= 1; off >>= 1) s += __shfl_xor(s, off);
            if (lane == 0) nrm[r] = rsqrtf(s + 1e-12f);
        }
        __syncthreads();
        const int c = tid & 31;
        #pragma unroll 4
        for (int it = 0; it < 32; ++it) {   // 8 d-rows x 32 codes per iter
            int d = it * 8 + (tid >> 5);
            cbt[d * QN + k0 + c] = tile[c * 257 + d] * nrm[c];
        }
    } else if (bid < 288) {
        int k = bid - 32;                   // patch-element row of M'
        int q = tid;
        float dot = 0.f, wsum = 0.f, psum = 0.f;
        #pragma unroll 4
        for (int cc = 0; cc < C; ++cc) {
            float wv_ = w[cc * 256 + k];    // wave-uniform (s_load)
            float pv  = proj[cc * QD + q];  // coalesced
            dot  += wv_ * pv;
            wsum += wv_;
            psum += pv;
        }
        Mp[k * 256 + q] = dot - (wsum * (1.0f / 512.0f)) * psum;
    } else {
        if (tid < Bb) {
            int cnt = ilens[tid] >> 4;
            if (cnt > Tp) cnt = Tp;
            if (cnt < 0) cnt = 0;
            out_len[tid] = Fp * cnt;
        }
    }
}

// prep_b: G = M'(256x256) x cbt(256x1024).  64 blocks x 4 k-rows.
__global__ void prep_b(const float* __restrict__ Mp, const float* __restrict__ cbt,
                       float* __restrict__ G) {
    __shared__ __align__(16) float mrow[4 * 256];
    const int tid = threadIdx.x, lane = tid & 63, cq = tid >> 6;
    const int k0 = blockIdx.x * 4;
    #pragma unroll
    for (int r = 0; r < 4; ++r)
        mrow[r * 256 + tid] = Mp[(k0 + r) * 256 + tid];
    __syncthreads();
    v4fe acc[4];
    const v4fe zero4 = {0.f, 0.f, 0.f, 0.f};
    #pragma unroll
    for (int r = 0; r < 4; ++r) acc[r] = zero4;
    const float* cbase = cbt + cq * 256 + 4 * lane;
    for (int d4 = 0; d4 < 64; ++d4) {
        const int db = d4 * 4;
        v4fe w0 = V4(cbase + (db + 0) * QN);
        v4fe w1 = V4(cbase + (db + 1) * QN);
        v4fe w2 = V4(cbase + (db + 2) * QN);
        v4fe w3 = V4(cbase + (db + 3) * QN);
        v4fe xv[4];
        #pragma unroll
        for (int r = 0; r < 4; ++r) xv[r] = V4(mrow + r * 256 + db);
        #pragma unroll
        for (int r = 0; r < 4; ++r) {
            acc[r] += xv[r].x * w0;
            acc[r] += xv[r].y * w1;
            acc[r] += xv[r].z * w2;
            acc[r] += xv[r].w * w3;
        }
    }
    #pragma unroll
    for (int r = 0; r < 4; ++r)
        *(v4fe*)(G + (size_t)(k0 + r) * QN + cq * 256 + 4 * lane) = acc[r];
}

// fused: patch staging -> sims = patch x G (K=256) -> argmax.
__global__ __launch_bounds__(256, 4) void fused_g(
    const float* __restrict__ xs,    // B*T*D
    const float* __restrict__ G,     // 256 x 1024 (k-major)
    int* __restrict__ out_ind)       // TOKS
{
    __shared__ __align__(16) float patch[TPB * 256];   // 16 KB
    __shared__ float rvs[4][TPB];
    __shared__ int   rif[4][TPB];

    const int tid  = threadIdx.x;
    const int lane = tid & 63;
    const int wv   = tid >> 6;               // wave id 0..3
    const int g0   = blockIdx.x * TPB;
    const int b    = g0 / NTOK;
    const int n0   = g0 - b * NTOK;
    const int tp0  = n0 >> 3;

    const v4fe zero4 = {0.f, 0.f, 0.f, 0.f};

    // ---- 1. patch staging (verified swizzle) ------------------------------
    {
        const v4fe* src = (const v4fe*)(xs + ((size_t)b * T + (size_t)tp0 * 16) * D);
        const float inv = 1.0f / (2.0f * FBANK_STD);
        #pragma unroll
        for (int r = 0; r < 4; ++r) {
            int f4 = r * 256 + tid;
            v4fe v = (src[f4] - FBANK_MEAN) * inv;
            int i = f4 >> 5;
            int d = (f4 & 31) << 2;
            int t = ((i >> 4) << 3) + (d >> 4);
            int k = ((i & 15) << 4) + (d & 15);
            *(v4fe*)&patch[t * 256 + k] = v;
        }
    }
    __syncthreads();

    // ---- 2. sims = patch x G: Mr=16 tok x 4 codes; waves = code-quarters --
    {
        const int cq = wv;
        v4fe acc[16];
        #pragma unroll
        for (int j = 0; j < 16; ++j) acc[j] = zero4;
        const float* cbase = G + cq * 256 + 4 * lane;
        for (int d4 = 0; d4 < 64; ++d4) {
            const int db = d4 * 4;
            v4fe w0 = V4(cbase + (db + 0) * QN);
            v4fe w1 = V4(cbase + (db + 1) * QN);
            v4fe w2 = V4(cbase + (db + 2) * QN);
            v4fe w3 = V4(cbase + (db + 3) * QN);
            #pragma unroll
            for (int hh = 0; hh < 2; ++hh) {
                v4fe xv[8];
                #pragma unroll
                for (int j = 0; j < 8; ++j)    // wave-uniform broadcasts
                    xv[j] = V4(patch + (hh * 8 + j) * 256 + db);
                #pragma unroll
                for (int j = 0; j < 8; ++j) {
                    acc[hh * 8 + j] += xv[j].x * w0;
                    acc[hh * 8 + j] += xv[j].y * w1;
                    acc[hh * 8 + j] += xv[j].z * w2;
                    acc[hh * 8 + j] += xv[j].w * w3;
                }
            }
        }
        // argmax: per-thread over 4 codes (ascending), 64-lane butterfly
        const int base = cq * 256 + 4 * lane;
        #pragma unroll
        for (int j = 0; j < 16; ++j) {
            float bv = acc[j].x; int bi = base;
            if (acc[j].y > bv) { bv = acc[j].y; bi = base + 1; }
            if (acc[j].z > bv) { bv = acc[j].z; bi = base + 2; }
            if (acc[j].w > bv) { bv = acc[j].w; bi = base + 3; }
            #pragma unroll
            for (int off = 32; off >= 1; off >>= 1) {
                float ov = __shfl_xor(bv, off);
                int   oi = __shfl_xor(bi, off);
                if (ov > bv || (ov == bv && oi < bi)) { bv = ov; bi = oi; }
            }
            if (lane == 0) { rvs[cq][j] = bv; rif[cq][j] = bi; }
        }
    }
    __syncthreads();
    if (tid < TPB) {
        float bv = rvs[0][tid];
        int   bi = rif[0][tid];
        #pragma unroll
        for (int w = 1; w < 4; ++w) {        // quarters ascending: strict >
            float ov = rvs[w][tid];
            if (ov > bv) { bv = ov; bi = rif[w][tid]; }
        }
        out_ind[g0 + tid] = bi;
    }
}

// ===========================================================================
// FALLBACK PATH: byte-identical round-11 kernels (1.25 MB workspace)
// ===========================================================================

__global__ void prep_r11(const float* __restrict__ w, const float* __restrict__ proj,
                         const float* __restrict__ cb, const int* __restrict__ ilens,
                         float* __restrict__ Mp, float* __restrict__ cbt,
                         int* __restrict__ out_len) {
    const int bid = blockIdx.x, tid = threadIdx.x;
    if (bid < 1024) {
        __shared__ float part[4];
        int k = bid;
        float v = cb[k * QD + tid];
        float s = v * v;
        #pragma unroll
        for (int off = 32; off >= 1; off >>= 1) s += __shfl_xor(s, off);
        if ((tid & 63) == 0) part[tid >> 6] = s;
        __syncthreads();
        float tot = part[0] + part[1] + part[2] + part[3];
        cbt[tid * QN + k] = v * rsqrtf(tot + 1e-12f);
    } else if (bid < 1280) {
        int k = bid - 1024;
        int q = tid;
        float dot = 0.f, wsum = 0.f, psum = 0.f;
        for (int c = 0; c < C; ++c) {
            float wv = w[c * 256 + k];
            float pv = proj[c * QD + q];
            dot  += wv * pv;
            wsum += wv;
            psum += pv;
        }
        Mp[k * 256 + q] = dot - (wsum * (1.0f / 512.0f)) * psum;
    } else {
        if (tid < Bb) {
            int cnt = ilens[tid] >> 4;
            if (cnt > Tp) cnt = Tp;
            if (cnt < 0) cnt = 0;
            out_len[tid] = Fp * cnt;
        }
    }
}

__global__ __launch_bounds__(256, 3) void fused_r11(
    const float* __restrict__ xs, const float* __restrict__ Mp,
    const float* __restrict__ cbt, int* __restrict__ out_ind) {
    __shared__ __align__(16) float patch[TPB * 256];
    __shared__ __align__(16) float xp[TPB * 256];
    __shared__ float rvs[4][TPB];
    __shared__ int   rif[4][TPB];
    const int tid = threadIdx.x, lane = tid & 63, wv = tid >> 6;
    const int g0 = blockIdx.x * TPB;
    const int b = g0 / NTOK, n0 = g0 - b * NTOK, tp0 = n0 >> 3;
    const v4fe zero4 = {0.f, 0.f, 0.f, 0.f};
    {
        const v4fe* src = (const v4fe*)(xs + ((size_t)b * T + (size_t)tp0 * 16) * D);
        const float inv = 1.0f / (2.0f * FBANK_STD);
        #pragma unroll
        for (int r = 0; r < 4; ++r) {
            int f4 = r * 256 + tid;
            v4fe v = (src[f4] - FBANK_MEAN) * inv;
            int i = f4 >> 5, d = (f4 & 31) << 2;
            int t = ((i >> 4) << 3) + (d >> 4);
            int k = ((i & 15) << 4) + (d & 15);
            *(v4fe*)&patch[t * 256 + k] = v;
        }
    }
    __syncthreads();
    {
        const int g = wv & 1, h = wv >> 1;
        v4fe acc[8];
        #pragma unroll
        for (int j = 0; j < 8; ++j) acc[j] = zero4;
        const float* pb = Mp + 4 * lane;
        const float* fb0 = &patch[(g * 8) * 256];
        for (int k4 = 0; k4 < 32; ++k4) {
            const int kb = h * 128 + k4 * 4;
            v4fe w0 = V4(pb + (kb + 0) * 256);
            v4fe w1 = V4(pb + (kb + 1) * 256);
            v4fe w2 = V4(pb + (kb + 2) * 256);
            v4fe w3 = V4(pb + (kb + 3) * 256);
            v4fe xv[8];
            #pragma unroll
            for (int j = 0; j < 8; ++j) xv[j] = V4(fb0 + j * 256 + kb);
            #pragma unroll
            for (int j = 0; j < 8; ++j) {
                acc[j] += xv[j].x * w0; acc[j] += xv[j].y * w1;
                acc[j] += xv[j].z * w2; acc[j] += xv[j].w * w3;
            }
        }
        float* xb = &xp[(g * 8) * 256 + 4 * lane];
        if (h == 0) {
            #pragma unroll
            for (int j = 0; j < 8; ++j) *(v4fe*)(xb + j * 256) = acc[j];
        }
        __syncthreads();
        if (h == 1) {
            #pragma unroll
            for (int j = 0; j < 8; ++j) {
                v4fe o = V4(xb + j * 256); o += acc[j];
                *(v4fe*)(xb + j * 256) = o;
            }
        }
    }
    __syncthreads();
    {
        const int cq = wv;
        v4fe acc[16];
        #pragma unroll
        for (int j = 0; j < 16; ++j) acc[j] = zero4;
        const float* cbase = cbt + cq * 256 + 4 * lane;
        for (int d4 = 0; d4 < 64; ++d4) {
            const int db = d4 * 4;
            v4fe w0 = V4(cbase + (db + 0) * QN);
            v4fe w1 = V4(cbase + (db + 1) * QN);
            v4fe w2 = V4(cbase + (db + 2) * QN);
            v4fe w3 = V4(cbase + (db + 3) * QN);
            #pragma unroll
            for (int hh = 0; hh < 2; ++hh) {
                v4fe xv[8];
                #pragma unroll
                for (int j = 0; j < 8; ++j) xv[j] = V4(xp + (hh * 8 + j) * 256 + db);
                #pragma unroll
                for (int j = 0; j < 8; ++j) {
                    acc[hh * 8 + j] += xv[j].x * w0;
                    acc[hh * 8 + j] += xv[j].y * w1;
                    acc[hh * 8 + j] += xv[j].z * w2;
                    acc[hh * 8 + j] += xv[j].w * w3;
                }
            }
        }
        const int base = cq * 256 + 4 * lane;
        #pragma unroll
        for (int j = 0; j < 16; ++j) {
            float bv = acc[j].x; int bi = base;
            if (acc[j].y > bv) { bv = acc[j].y; bi = base + 1; }
            if (acc[j].z > bv) { bv = acc[j].z; bi = base + 2; }
            if (acc[j].w > bv) { bv = acc[j].w; bi = base + 3; }
            #pragma unroll
            for (int off = 32; off >= 1; off >>= 1) {
                float ov = __shfl_xor(bv, off);
                int   oi = __shfl_xor(bi, off);
                if (ov > bv || (ov == bv && oi < bi)) { bv = ov; bi = oi; }
            }
            if (lane == 0) { rvs[cq][j] = bv; rif[cq][j] = bi; }
        }
    }
    __syncthreads();
    if (tid < TPB) {
        float bv = rvs[0][tid];
        int   bi = rif[0][tid];
        #pragma unroll
        for (int w = 1; w < 4; ++w) {
            float ov = rvs[w][tid];
            if (ov > bv) { bv = ov; bi = rif[w][tid]; }
        }
        out_ind[g0 + tid] = bi;
    }
}

// ---------------------------------------------------------------------------
extern "C" void kernel_launch(void* const* d_in, const int* in_sizes, int n_in,
                              void* d_out, int out_size, void* d_ws, size_t ws_size,
                              hipStream_t stream) {
    const float* xs       = (const float*)d_in[0];   // (32,3200,128) f32
    const int*   ilens    = (const int*)  d_in[1];   // (32,) i32
    const float* conv_w   = (const float*)d_in[2];   // (512,1,16,16) f32
    const float* proj     = (const float*)d_in[3];   // (512,256) f32
    const float* codebook = (const float*)d_in[4];   // (1024,256) f32
    int* out = (int*)d_out;                          // 51200 ind + 32 len

    const size_t need = (size_t)(QD * QN + 256 * 256 + 256 * QN) * 4;  // 2.25 MB
    if (ws_size >= need) {
        float* cbt = (float*)d_ws;            // 256x1024 = 1 MB
        float* Mp  = cbt + QD * QN;           // 256x256  = 256 KB
        float* G   = Mp + 256 * 256;          // 256x1024 = 1 MB
        prep_a<<<289, 256, 0, stream>>>(conv_w, proj, codebook, ilens,
                                        Mp, cbt, out + TOKS);
        prep_b<<<64, 256, 0, stream>>>(Mp, cbt, G);
        fused_g<<<TOKS / TPB, 256, 0, stream>>>(xs, G, out);
    } else {
        // round-11 verified path (1.25 MB workspace)
        float* Mp  = (float*)d_ws;
        float* cbt = Mp + 256 * 256;
        prep_r11<<<1281, 256, 0, stream>>>(conv_w, proj, codebook, ilens,
                                           Mp, cbt, out + TOKS);
        fused_r11<<<TOKS / TPB, 256, 0, stream>>>(xs, Mp, cbt, out);
    }
}